// Round 1
// baseline (1950.473 us; speedup 1.0000x reference)
//
#include <hip/hip_runtime.h>
#include <math.h>

#define BB_ 4096
#define SS_ 512
#define KK_ 10
#define MM_ 20
#define UU_ 256
#define CC_ 128

// d_out flat offsets (floats), in reference return order
#define EOS_OFF   0
#define PI_OFF    20480
#define MU1_OFF   430080
#define MU2_OFF   839680
#define S1_OFF    1249280
#define S2_OFF    1658880
#define RHO_OFF   2068480
#define H1_OFF    2478080
#define H2_OFF    4575232
#define OSC_OFF   6672384
#define W_OFF     15060992
#define PHI_OFF   15585280
#define KAPPA_OFF 16633856

__device__ __forceinline__ float sigmoidf_(float x) {
    return 1.0f / (1.0f + __expf(-x));
}

// ---------------------------------------------------------------------------
// Generic FF gated cell: out = j*(1-h) + (1-k)*h
//   j = sigmoid(xin@jxW + jxb + h@jhW + jhb), k likewise.
// xin assembled on the fly from up to 3 segments: x[b,0:3], s1, s2.
// Tile: 16 batch rows per block, 256 output columns per block (grid.y halves).
// ---------------------------------------------------------------------------
#define FF_BB 16
#define FF_PAD 644

__global__ __launch_bounds__(256) void ff_cell_kernel(
    const float* __restrict__ x,
    const float* __restrict__ s1, int len1, int str1,
    const float* __restrict__ s2, int str2,
    const float* __restrict__ h_in,
    const float* __restrict__ jxW, const float* __restrict__ jxb,
    const float* __restrict__ jhW, const float* __restrict__ jhb,
    const float* __restrict__ kxW, const float* __restrict__ kxb,
    const float* __restrict__ khW, const float* __restrict__ khb,
    float* __restrict__ out, int D_in)
{
    __shared__ float lds[FF_BB * FF_PAD];   // 41.2 KB
    const int tid = threadIdx.x;
    const int b0 = blockIdx.x * FF_BB;
    const int s = blockIdx.y * 256 + tid;

    // stage concatenated input tile [16][D_in]
    for (int idx = tid; idx < FF_BB * D_in; idx += 256) {
        int bb = idx / D_in;
        int r = idx - bb * D_in;
        int b = b0 + bb;
        float v;
        if (r < 3)               v = x[b * 3 + r];
        else if (r < 3 + len1)   v = s1[b * str1 + (r - 3)];
        else                     v = s2[b * str2 + (r - 3 - len1)];
        lds[bb * FF_PAD + r] = v;
    }
    __syncthreads();

    float accj[FF_BB], acck[FF_BB];
    const float bj = jxb[s] + jhb[s];
    const float bk = kxb[s] + khb[s];
#pragma unroll
    for (int bb = 0; bb < FF_BB; bb++) { accj[bb] = bj; acck[bb] = bk; }

#pragma unroll 4
    for (int r = 0; r < D_in; r++) {
        float wj = jxW[r * SS_ + s];
        float wk = kxW[r * SS_ + s];
#pragma unroll
        for (int bb = 0; bb < FF_BB; bb++) {
            float xv = lds[bb * FF_PAD + r];
            accj[bb] = fmaf(xv, wj, accj[bb]);
            acck[bb] = fmaf(xv, wk, acck[bb]);
        }
    }
    __syncthreads();

    // stage h tile [16][512] (reuse LDS)
    for (int idx = tid; idx < FF_BB * SS_; idx += 256) {
        int bb = idx >> 9;
        int r = idx & 511;
        lds[bb * FF_PAD + r] = h_in[(b0 + bb) * SS_ + r];
    }
    __syncthreads();

#pragma unroll 4
    for (int r = 0; r < SS_; r++) {
        float wj = jhW[r * SS_ + s];
        float wk = khW[r * SS_ + s];
#pragma unroll
        for (int bb = 0; bb < FF_BB; bb++) {
            float hv = lds[bb * FF_PAD + r];
            accj[bb] = fmaf(hv, wj, accj[bb]);
            acck[bb] = fmaf(hv, wk, acck[bb]);
        }
    }

#pragma unroll
    for (int bb = 0; bb < FF_BB; bb++) {
        float hv = lds[bb * FF_PAD + s];
        float j = sigmoidf_(accj[bb]);
        float k = sigmoidf_(acck[bb]);
        out[(b0 + bb) * SS_ + s] = j * (1.0f - hv) + (1.0f - k) * hv;
    }
}

// ---------------------------------------------------------------------------
// Gaussian window attention: one block per batch row.
// ---------------------------------------------------------------------------
__global__ __launch_bounds__(256) void win_kernel(
    const float* __restrict__ h1,
    const float* __restrict__ winW, const float* __restrict__ winb,
    const float* __restrict__ init_kappa,
    const float* __restrict__ c_vec,
    float* __restrict__ out)
{
    __shared__ float hl[512];
    __shared__ float part[8][30];
    __shared__ float kg[30];
    __shared__ float alpha_s[10], beta_s[10], kap_s[10];
    __shared__ float phil[256];
    __shared__ float wpart[256];

    const int tid = threadIdx.x;
    const int b = blockIdx.x;

    hl[tid] = h1[b * 512 + tid];
    hl[256 + tid] = h1[b * 512 + 256 + tid];
    __syncthreads();

    if (tid < 240) {
        int c = tid % 30, p = tid / 30;
        float a = 0.0f;
        int s0 = p * 64;
#pragma unroll 4
        for (int i = 0; i < 64; i++) a = fmaf(hl[s0 + i], winW[(s0 + i) * 30 + c], a);
        part[p][c] = a;
    }
    __syncthreads();
    if (tid < 30) {
        float a = winb[tid];
#pragma unroll
        for (int p = 0; p < 8; p++) a += part[p][tid];
        kg[tid] = a;
    }
    __syncthreads();
    if (tid < 10) {
        alpha_s[tid] = __expf(kg[tid]);
        beta_s[tid] = __expf(kg[10 + tid]);
        float kp = init_kappa[b * 10 + tid] + __expf(kg[20 + tid]);
        kap_s[tid] = kp;
        out[KAPPA_OFF + b * 10 + tid] = kp;
    }
    __syncthreads();
    {
        float u = (float)tid;
        float p = 0.0f;
#pragma unroll
        for (int k = 0; k < 10; k++) {
            float d = kap_s[k] - u;
            p += alpha_s[k] * __expf(-beta_s[k] * d * d);
        }
        phil[tid] = p;
        out[PHI_OFF + b * 256 + tid] = p;
    }
    __syncthreads();
    {
        int c = tid & 127, half = tid >> 7;
        const float* cv = c_vec + (size_t)b * UU_ * CC_ + (size_t)half * 128 * CC_ + c;
        float a = 0.0f;
#pragma unroll 4
        for (int uu = 0; uu < 128; uu++) a = fmaf(phil[half * 128 + uu], cv[uu * CC_], a);
        wpart[tid] = a;
    }
    __syncthreads();
    if (tid < 128) out[W_OFF + b * CC_ + tid] = wpart[tid] + wpart[128 + tid];
}

// ---------------------------------------------------------------------------
// Oscillator gates: osc_new[n,b,t], n = blockIdx.z
// ---------------------------------------------------------------------------
__global__ __launch_bounds__(256) void osc_kernel(
    const float* __restrict__ h2,
    const float* __restrict__ osc_h,
    const float* __restrict__ jxW, const float* __restrict__ jxb,
    const float* __restrict__ jhW, const float* __restrict__ jhb,
    const float* __restrict__ kxW, const float* __restrict__ kxb,
    const float* __restrict__ khW, const float* __restrict__ khb,
    float* __restrict__ osc_new)
{
    __shared__ float h2l[16 * 512];  // 32 KB
    __shared__ float ohl[16 * 512];  // 32 KB
    const int tid = threadIdx.x;
    const int b0 = blockIdx.x * 16;
    const int t = blockIdx.y * 256 + tid;
    const int n = blockIdx.z;

    const float* jxWn = jxW + (size_t)n * SS_ * SS_;
    const float* jhWn = jhW + (size_t)n * SS_ * SS_;
    const float* kxWn = kxW + (size_t)n * SS_ * SS_;
    const float* khWn = khW + (size_t)n * SS_ * SS_;

    for (int idx = tid; idx < 16 * 512; idx += 256) {
        int bb = idx >> 9, r = idx & 511;
        h2l[bb * 512 + r] = h2[(b0 + bb) * SS_ + r];
        ohl[bb * 512 + r] = osc_h[((size_t)n * BB_ + b0 + bb) * SS_ + r];
    }
    __syncthreads();

    float accj[16], acck[16];
    const float bj = jxb[n * SS_ + t] + jhb[n * SS_ + t];
    const float bk = kxb[n * SS_ + t] + khb[n * SS_ + t];
#pragma unroll
    for (int bb = 0; bb < 16; bb++) { accj[bb] = bj; acck[bb] = bk; }

#pragma unroll 2
    for (int r = 0; r < SS_; r++) {
        float wjx = jxWn[r * SS_ + t];
        float wkx = kxWn[r * SS_ + t];
        float wjh = jhWn[r * SS_ + t];
        float wkh = khWn[r * SS_ + t];
#pragma unroll
        for (int bb = 0; bb < 16; bb++) {
            float hv = h2l[bb * 512 + r];
            float ov = ohl[bb * 512 + r];
            accj[bb] = fmaf(hv, wjx, accj[bb]);
            accj[bb] = fmaf(ov, wjh, accj[bb]);
            acck[bb] = fmaf(hv, wkx, acck[bb]);
            acck[bb] = fmaf(ov, wkh, acck[bb]);
        }
    }

#pragma unroll
    for (int bb = 0; bb < 16; bb++) {
        float oh = ohl[bb * 512 + t];
        float j = sigmoidf_(accj[bb]);
        float k = sigmoidf_(acck[bb]);
        osc_new[((size_t)n * BB_ + b0 + bb) * SS_ + t] = j * (1.0f - oh) + (1.0f - k) * oh;
    }
}

// ---------------------------------------------------------------------------
// MDN head: 4 batch rows per block; recompute 5-step oscillator recurrence
// into LDS, GEMM vs lin_W, then eos/softmax/sigma/rho epilogue.
// ---------------------------------------------------------------------------
__global__ __launch_bounds__(256) void mdn_kernel(
    const float* __restrict__ osc_new,
    const float* __restrict__ linW, const float* __restrict__ linb,
    float* __restrict__ out)
{
    __shared__ float zl[20][512];   // 40 KB
    __shared__ float ol[20][121];   // 9.7 KB
    const int tid = threadIdx.x;
    const int b0 = blockIdx.x * 4;

    for (int idx = tid; idx < 4 * 512; idx += 256) {
        int bb = idx >> 9, sI = idx & 511;
        int b = b0 + bb;
        float ph = osc_new[((size_t)0 * BB_ + b) * SS_ + sI];
        float om = osc_new[((size_t)1 * BB_ + b) * SS_ + sI];
        float r  = osc_new[((size_t)2 * BB_ + b) * SS_ + sI];
        float mu = osc_new[((size_t)3 * BB_ + b) * SS_ + sI];
        zl[bb * 5 + 0][sI] = r * __cosf(ph);
#pragma unroll
        for (int tt = 1; tt < 5; tt++) {
            r = fmaf(mu - r * r, r, r);
            ph += om;
            zl[bb * 5 + tt][sI] = r * __cosf(ph);
        }
    }
    __syncthreads();

    if (tid < 242) {
        int c = tid % 121, rh = tid / 121;
        float acc[10];
        const float lb = linb[c];
#pragma unroll
        for (int rr = 0; rr < 10; rr++) acc[rr] = lb;
#pragma unroll 4
        for (int s = 0; s < 512; s++) {
            float wv = linW[s * 121 + c];
#pragma unroll
            for (int rr = 0; rr < 10; rr++)
                acc[rr] = fmaf(zl[rh * 10 + rr][s], wv, acc[rr]);
        }
#pragma unroll
        for (int rr = 0; rr < 10; rr++) ol[rh * 10 + rr][c] = acc[rr];
    }
    __syncthreads();

    if (tid < 20) {
        const int row = tid;
        const int rg = b0 * 5 + row;
        const float* o = ol[row];
        out[EOS_OFF + rg] = 1.0f / (1.0f + __expf(o[0]));
        float mx = -1e30f;
#pragma unroll
        for (int m = 0; m < 20; m++) mx = fmaxf(mx, o[1 + m]);
        float ex[20];
        float sum = 0.0f;
#pragma unroll
        for (int m = 0; m < 20; m++) { ex[m] = __expf(o[1 + m] - mx); sum += ex[m]; }
        float inv = 1.0f / sum;
#pragma unroll
        for (int m = 0; m < 20; m++) {
            out[PI_OFF  + rg * 20 + m] = ex[m] * inv;
            out[MU1_OFF + rg * 20 + m] = o[21 + m];
            out[MU2_OFF + rg * 20 + m] = o[41 + m];
            out[S1_OFF  + rg * 20 + m] = __expf(o[61 + m]);
            out[S2_OFF  + rg * 20 + m] = __expf(o[81 + m]);
            out[RHO_OFF + rg * 20 + m] = tanhf(o[101 + m]);
        }
    }
}

// ---------------------------------------------------------------------------
extern "C" void kernel_launch(void* const* d_in, const int* in_sizes, int n_in,
                              void* d_out, int out_size, void* d_ws, size_t ws_size,
                              hipStream_t stream)
{
    const float* x          = (const float*)d_in[0];
    const float* c_vec      = (const float*)d_in[1];
    const float* rnn_1_h    = (const float*)d_in[2];
    const float* rnn_2_h    = (const float*)d_in[3];
    const float* osc_h      = (const float*)d_in[4];
    const float* init_w     = (const float*)d_in[5];
    const float* init_kappa = (const float*)d_in[6];
    const float* r1_jx_W = (const float*)d_in[7];
    const float* r1_jx_b = (const float*)d_in[8];
    const float* r1_jh_W = (const float*)d_in[9];
    const float* r1_jh_b = (const float*)d_in[10];
    const float* r1_kx_W = (const float*)d_in[11];
    const float* r1_kx_b = (const float*)d_in[12];
    const float* r1_kh_W = (const float*)d_in[13];
    const float* r1_kh_b = (const float*)d_in[14];
    const float* r2_jx_W = (const float*)d_in[15];
    const float* r2_jx_b = (const float*)d_in[16];
    const float* r2_jh_W = (const float*)d_in[17];
    const float* r2_jh_b = (const float*)d_in[18];
    const float* r2_kx_W = (const float*)d_in[19];
    const float* r2_kx_b = (const float*)d_in[20];
    const float* r2_kh_W = (const float*)d_in[21];
    const float* r2_kh_b = (const float*)d_in[22];
    const float* osc_jx_W = (const float*)d_in[23];
    const float* osc_jx_b = (const float*)d_in[24];
    const float* osc_jh_W = (const float*)d_in[25];
    const float* osc_jh_b = (const float*)d_in[26];
    const float* osc_kx_W = (const float*)d_in[27];
    const float* osc_kx_b = (const float*)d_in[28];
    const float* osc_kh_W = (const float*)d_in[29];
    const float* osc_kh_b = (const float*)d_in[30];
    const float* win_W = (const float*)d_in[31];
    const float* win_b = (const float*)d_in[32];
    const float* lin_W = (const float*)d_in[33];
    const float* lin_b = (const float*)d_in[34];

    float* out = (float*)d_out;

    dim3 ffgrid(BB_ / FF_BB, SS_ / 256);

    // rnn1: xin = [x(3) | init_w(128)], D_in = 131
    ff_cell_kernel<<<ffgrid, 256, 0, stream>>>(
        x, init_w, 128, 128, init_w, 0, rnn_1_h,
        r1_jx_W, r1_jx_b, r1_jh_W, r1_jh_b,
        r1_kx_W, r1_kx_b, r1_kh_W, r1_kh_b,
        out + H1_OFF, 131);

    // attention window -> kappa, phi, w
    win_kernel<<<BB_, 256, 0, stream>>>(out + H1_OFF, win_W, win_b,
                                        init_kappa, c_vec, out);

    // rnn2: xin = [x(3) | h1(512) | w(128)], D_in = 643
    ff_cell_kernel<<<ffgrid, 256, 0, stream>>>(
        x, out + H1_OFF, 512, 512, out + W_OFF, 128, rnn_2_h,
        r2_jx_W, r2_jx_b, r2_jh_W, r2_jh_b,
        r2_kx_W, r2_kx_b, r2_kh_W, r2_kh_b,
        out + H2_OFF, 643);

    // oscillator gates -> osc_new [4,B,S]
    osc_kernel<<<dim3(BB_ / 16, 2, 4), 256, 0, stream>>>(
        out + H2_OFF, osc_h,
        osc_jx_W, osc_jx_b, osc_jh_W, osc_jh_b,
        osc_kx_W, osc_kx_b, osc_kh_W, osc_kh_b,
        out + OSC_OFF);

    // oscillator recurrence + MDN head
    mdn_kernel<<<BB_ / 4, 256, 0, stream>>>(out + OSC_OFF, lin_W, lin_b, out);
}

// Round 3
// 1203.812 us; speedup vs baseline: 1.6202x; 1.6202x over previous
//
#include <hip/hip_runtime.h>
#include <math.h>

#define BB_ 4096
#define SS_ 512
#define KK_ 10
#define MM_ 20
#define UU_ 256
#define CC_ 128

// d_out flat offsets (floats), in reference return order
#define EOS_OFF   0
#define PI_OFF    20480
#define MU1_OFF   430080
#define MU2_OFF   839680
#define S1_OFF    1249280
#define S2_OFF    1658880
#define RHO_OFF   2068480
#define H1_OFF    2478080
#define H2_OFF    4575232
#define OSC_OFF   6672384
#define W_OFF     15060992
#define PHI_OFF   15585280
#define KAPPA_OFF 16633856

// Padded K sizes (multiples of 32)
#define KP1 672     // rnn1: 3 + 128 + 512 = 643 -> 672
#define KP2 1184    // rnn2: 3 + 512 + 128 + 512 = 1155 -> 1184
#define KPO 1024    // osc: 512 + 512

typedef __attribute__((ext_vector_type(8))) short s8b;   // 8 x bf16
typedef __attribute__((ext_vector_type(4))) float f4;    // 4 x f32

__device__ __forceinline__ float sigmoidf_(float x) {
    return 1.0f / (1.0f + __expf(-x));
}

__device__ __forceinline__ unsigned short f2b(float v) {
    union { float f; unsigned int u; } c; c.f = v;
    unsigned int r = (c.u + 0x7FFFu + ((c.u >> 16) & 1u)) >> 16;
    return (unsigned short)r;
}

// ---------------------------------------------------------------------------
// Pack X1 = [x(3) | init_w(128) | rnn_1_h(512) | 0-pad] -> bf16 [4096][672]
// ---------------------------------------------------------------------------
__global__ __launch_bounds__(256) void pack_x1(
    const float* __restrict__ x, const float* __restrict__ init_w,
    const float* __restrict__ h, unsigned short* __restrict__ X)
{
    int idx = blockIdx.x * 256 + threadIdx.x;
    if (idx >= BB_ * KP1) return;
    int b = idx / KP1, c = idx - b * KP1;
    float v = 0.0f;
    if (c < 3)        v = x[b * 3 + c];
    else if (c < 131) v = init_w[b * 128 + (c - 3)];
    else if (c < 643) v = h[b * 512 + (c - 131)];
    X[idx] = f2b(v);
}

// Pack X2 = [x(3) | h1(512) | w(128) | rnn_2_h(512) | 0-pad] -> bf16 [4096][1184]
__global__ __launch_bounds__(256) void pack_x2(
    const float* __restrict__ x, const float* __restrict__ h1,
    const float* __restrict__ w, const float* __restrict__ h2p,
    unsigned short* __restrict__ X)
{
    int idx = blockIdx.x * 256 + threadIdx.x;
    if (idx >= BB_ * KP2) return;
    int b = idx / KP2, c = idx - b * KP2;
    float v = 0.0f;
    if (c < 3)         v = x[b * 3 + c];
    else if (c < 515)  v = h1[b * 512 + (c - 3)];
    else if (c < 643)  v = w[b * 128 + (c - 515)];
    else if (c < 1155) v = h2p[b * 512 + (c - 643)];
    X[idx] = f2b(v);
}

// Pack Xosc[z] = [h2(512) | osc_h[z](512)] -> bf16 [4][4096][1024]
__global__ __launch_bounds__(256) void pack_xosc(
    const float* __restrict__ h2, const float* __restrict__ osc_h,
    unsigned short* __restrict__ X)
{
    int idx = blockIdx.x * 256 + threadIdx.x;   // 4*4096*1024 = 2^24
    int c = idx & 1023;
    int b = (idx >> 10) & 4095;
    int z = idx >> 22;
    float v = (c < 512) ? h2[b * 512 + c]
                        : osc_h[((size_t)z * BB_ + b) * 512 + (c - 512)];
    X[idx] = f2b(v);
}

// ---------------------------------------------------------------------------
// Pack + transpose weights: dst[z][nc][k] (bf16, [512][Kp]) =
//   k < d1        : src_x[z][k][nc]
//   k < d1+512    : src_h[z][k-d1][nc]
//   else          : 0
// Tile: 64 nc x 32 k per block via LDS.
// ---------------------------------------------------------------------------
__global__ __launch_bounds__(256) void pack_w(
    const float* __restrict__ src_x, int d1, size_t sxz,
    const float* __restrict__ src_h, size_t shz,
    unsigned short* __restrict__ dst, int Kp, size_t dz)
{
    __shared__ float t[32][65];
    const int tid = threadIdx.x;
    const int nc0 = blockIdx.x * 64;
    const int k0 = blockIdx.y * 32;
    const int z = blockIdx.z;
    const float* sx = src_x + (size_t)z * sxz;
    const float* sh = src_h + (size_t)z * shz;
    unsigned short* dd = dst + (size_t)z * dz;

    for (int i = tid; i < 64 * 32; i += 256) {
        int ncl = i & 63, kl = i >> 6;
        int k = k0 + kl;
        float v = 0.0f;
        if (k < d1)            v = sx[(size_t)k * 512 + nc0 + ncl];
        else if (k < d1 + 512) v = sh[(size_t)(k - d1) * 512 + nc0 + ncl];
        t[kl][ncl] = v;
    }
    __syncthreads();
    for (int i = tid; i < 64 * 32; i += 256) {
        int kl = i & 31, ncl = i >> 5;
        dd[(size_t)(nc0 + ncl) * Kp + k0 + kl] = f2b(t[kl][ncl]);
    }
}

// ---------------------------------------------------------------------------
// MFMA gated-cell GEMM:
//   pre_j = X @ Wj^T + jxb + jhb ;  pre_k = X @ Wk^T + kxb + khb
//   out = sigmoid(pre_j)*(1-h) + (1-sigmoid(pre_k))*h
// X: bf16 [z][4096][Kp] row-major. Wj/Wk: bf16 [z][512][Kp] (pre-transposed).
// Block: 128 batch rows x 128 out cols (both gates). 4 waves 2x2, each 64x64.
// ---------------------------------------------------------------------------
__global__ __launch_bounds__(256) void gemm_gate(
    const unsigned short* __restrict__ A, size_t az, int Kp,
    const unsigned short* __restrict__ Wj, const unsigned short* __restrict__ Wk, size_t wz,
    const float* __restrict__ jxb, const float* __restrict__ jhb,
    const float* __restrict__ kxb, const float* __restrict__ khb,
    const float* __restrict__ h_prev, size_t hz,
    float* __restrict__ out, size_t oz)
{
    __shared__ unsigned short As[128 * 40];
    __shared__ unsigned short Bjs[128 * 40];
    __shared__ unsigned short Bks[128 * 40];

    const int tid = threadIdx.x;
    const int lane = tid & 63;
    const int w = tid >> 6;
    const int wr = w >> 1, wc = w & 1;
    const int b0 = blockIdx.x * 128;
    const int s0 = blockIdx.y * 128;
    const int z = blockIdx.z;

    const unsigned short* Az = A + (size_t)z * az;
    const unsigned short* Wjz = Wj + (size_t)z * wz;
    const unsigned short* Wkz = Wk + (size_t)z * wz;

    f4 accj[4][4], acck[4][4];
#pragma unroll
    for (int m = 0; m < 4; m++)
#pragma unroll
        for (int c = 0; c < 4; c++) {
            accj[m][c] = (f4)0.0f;
            acck[m][c] = (f4)0.0f;
        }

    const int lr = lane & 15;
    const int ks = (lane >> 4) * 8;
    const int nK = Kp >> 5;

    for (int kt = 0; kt < nK; kt++) {
        const int k0 = kt * 32;
        // stage A / Bj / Bk tiles: 128 rows x 32 k each
#pragma unroll
        for (int i = tid; i < 512; i += 256) {
            int row = i >> 2, seg = i & 3;
            *(uint4*)&As[row * 40 + seg * 8] =
                *(const uint4*)(Az + (size_t)(b0 + row) * Kp + k0 + seg * 8);
            *(uint4*)&Bjs[row * 40 + seg * 8] =
                *(const uint4*)(Wjz + (size_t)(s0 + row) * Kp + k0 + seg * 8);
            *(uint4*)&Bks[row * 40 + seg * 8] =
                *(const uint4*)(Wkz + (size_t)(s0 + row) * Kp + k0 + seg * 8);
        }
        __syncthreads();

        s8b af[4], bjf[4], bkf[4];
#pragma unroll
        for (int m = 0; m < 4; m++)
            af[m] = *(const s8b*)&As[(wr * 64 + m * 16 + lr) * 40 + ks];
#pragma unroll
        for (int c = 0; c < 4; c++) {
            bjf[c] = *(const s8b*)&Bjs[(wc * 64 + c * 16 + lr) * 40 + ks];
            bkf[c] = *(const s8b*)&Bks[(wc * 64 + c * 16 + lr) * 40 + ks];
        }
#pragma unroll
        for (int m = 0; m < 4; m++)
#pragma unroll
            for (int c = 0; c < 4; c++) {
                accj[m][c] = __builtin_amdgcn_mfma_f32_16x16x32_bf16(af[m], bjf[c], accj[m][c], 0, 0, 0);
                acck[m][c] = __builtin_amdgcn_mfma_f32_16x16x32_bf16(af[m], bkf[c], acck[m][c], 0, 0, 0);
            }
        __syncthreads();
    }

    // Epilogue: bias + sigmoid + gate vs h_prev
    const float* hp = h_prev + (size_t)z * hz;
    float* op = out + (size_t)z * oz;
    const int zb = z * 512;
#pragma unroll
    for (int c = 0; c < 4; c++) {
        const int scol = s0 + wc * 64 + c * 16 + lr;
        const float bj = jxb[zb + scol] + jhb[zb + scol];
        const float bk = kxb[zb + scol] + khb[zb + scol];
#pragma unroll
        for (int m = 0; m < 4; m++) {
            const int r0 = b0 + wr * 64 + m * 16 + (lane >> 4) * 4;
#pragma unroll
            for (int reg = 0; reg < 4; reg++) {
                const int r = r0 + reg;
                const float h = hp[(size_t)r * 512 + scol];
                const float jv = sigmoidf_(accj[m][c][reg] + bj);
                const float kv = sigmoidf_(acck[m][c][reg] + bk);
                op[(size_t)r * 512 + scol] = jv * (1.0f - h) + (1.0f - kv) * h;
            }
        }
    }
}

// ---------------------------------------------------------------------------
// Gaussian window attention: one block per batch row.
// ---------------------------------------------------------------------------
__global__ __launch_bounds__(256) void win_kernel(
    const float* __restrict__ h1,
    const float* __restrict__ winW, const float* __restrict__ winb,
    const float* __restrict__ init_kappa,
    const float* __restrict__ c_vec,
    float* __restrict__ out)
{
    __shared__ float hl[512];
    __shared__ float part[8][30];
    __shared__ float kg[30];
    __shared__ float alpha_s[10], beta_s[10], kap_s[10];
    __shared__ float phil[256];
    __shared__ float wpart[256];

    const int tid = threadIdx.x;
    const int b = blockIdx.x;

    hl[tid] = h1[b * 512 + tid];
    hl[256 + tid] = h1[b * 512 + 256 + tid];
    __syncthreads();

    if (tid < 240) {
        int c = tid % 30, p = tid / 30;
        float a = 0.0f;
        int s0 = p * 64;
#pragma unroll 4
        for (int i = 0; i < 64; i++) a = fmaf(hl[s0 + i], winW[(s0 + i) * 30 + c], a);
        part[p][c] = a;
    }
    __syncthreads();
    if (tid < 30) {
        float a = winb[tid];
#pragma unroll
        for (int p = 0; p < 8; p++) a += part[p][tid];
        kg[tid] = a;
    }
    __syncthreads();
    if (tid < 10) {
        alpha_s[tid] = __expf(kg[tid]);
        beta_s[tid] = __expf(kg[10 + tid]);
        float kp = init_kappa[b * 10 + tid] + __expf(kg[20 + tid]);
        kap_s[tid] = kp;
        out[KAPPA_OFF + b * 10 + tid] = kp;
    }
    __syncthreads();
    {
        float u = (float)tid;
        float p = 0.0f;
#pragma unroll
        for (int k = 0; k < 10; k++) {
            float d = kap_s[k] - u;
            p += alpha_s[k] * __expf(-beta_s[k] * d * d);
        }
        phil[tid] = p;
        out[PHI_OFF + b * 256 + tid] = p;
    }
    __syncthreads();
    {
        int c = tid & 127, half = tid >> 7;
        const float* cv = c_vec + (size_t)b * UU_ * CC_ + (size_t)half * 128 * CC_ + c;
        float a = 0.0f;
#pragma unroll 4
        for (int uu = 0; uu < 128; uu++) a = fmaf(phil[half * 128 + uu], cv[uu * CC_], a);
        wpart[tid] = a;
    }
    __syncthreads();
    if (tid < 128) out[W_OFF + b * CC_ + tid] = wpart[tid] + wpart[128 + tid];
}

// ---------------------------------------------------------------------------
// MDN head: 4 batch rows per block; recompute 5-step oscillator recurrence
// into LDS, GEMM vs lin_W, then eos/softmax/sigma/rho epilogue.
// ---------------------------------------------------------------------------
__global__ __launch_bounds__(256) void mdn_kernel(
    const float* __restrict__ osc_new,
    const float* __restrict__ linW, const float* __restrict__ linb,
    float* __restrict__ out)
{
    __shared__ float zl[20][512];   // 40 KB
    __shared__ float ol[20][121];   // 9.7 KB
    const int tid = threadIdx.x;
    const int b0 = blockIdx.x * 4;

    for (int idx = tid; idx < 4 * 512; idx += 256) {
        int bb = idx >> 9, sI = idx & 511;
        int b = b0 + bb;
        float ph = osc_new[((size_t)0 * BB_ + b) * SS_ + sI];
        float om = osc_new[((size_t)1 * BB_ + b) * SS_ + sI];
        float r  = osc_new[((size_t)2 * BB_ + b) * SS_ + sI];
        float mu = osc_new[((size_t)3 * BB_ + b) * SS_ + sI];
        zl[bb * 5 + 0][sI] = r * __cosf(ph);
#pragma unroll
        for (int tt = 1; tt < 5; tt++) {
            r = fmaf(mu - r * r, r, r);
            ph += om;
            zl[bb * 5 + tt][sI] = r * __cosf(ph);
        }
    }
    __syncthreads();

    if (tid < 242) {
        int c = tid % 121, rh = tid / 121;
        float acc[10];
        const float lb = linb[c];
#pragma unroll
        for (int rr = 0; rr < 10; rr++) acc[rr] = lb;
#pragma unroll 4
        for (int s = 0; s < 512; s++) {
            float wv = linW[s * 121 + c];
#pragma unroll
            for (int rr = 0; rr < 10; rr++)
                acc[rr] = fmaf(zl[rh * 10 + rr][s], wv, acc[rr]);
        }
#pragma unroll
        for (int rr = 0; rr < 10; rr++) ol[rh * 10 + rr][c] = acc[rr];
    }
    __syncthreads();

    if (tid < 20) {
        const int row = tid;
        const int rg = b0 * 5 + row;
        const float* o = ol[row];
        out[EOS_OFF + rg] = 1.0f / (1.0f + __expf(o[0]));
        float mx = -1e30f;
#pragma unroll
        for (int m = 0; m < 20; m++) mx = fmaxf(mx, o[1 + m]);
        float ex[20];
        float sum = 0.0f;
#pragma unroll
        for (int m = 0; m < 20; m++) { ex[m] = __expf(o[1 + m] - mx); sum += ex[m]; }
        float inv = 1.0f / sum;
#pragma unroll
        for (int m = 0; m < 20; m++) {
            out[PI_OFF  + rg * 20 + m] = ex[m] * inv;
            out[MU1_OFF + rg * 20 + m] = o[21 + m];
            out[MU2_OFF + rg * 20 + m] = o[41 + m];
            out[S1_OFF  + rg * 20 + m] = __expf(o[61 + m]);
            out[S2_OFF  + rg * 20 + m] = __expf(o[81 + m]);
            out[RHO_OFF + rg * 20 + m] = tanhf(o[101 + m]);
        }
    }
}

// ---------------------------------------------------------------------------
extern "C" void kernel_launch(void* const* d_in, const int* in_sizes, int n_in,
                              void* d_out, int out_size, void* d_ws, size_t ws_size,
                              hipStream_t stream)
{
    const float* x          = (const float*)d_in[0];
    const float* c_vec      = (const float*)d_in[1];
    const float* rnn_1_h    = (const float*)d_in[2];
    const float* rnn_2_h    = (const float*)d_in[3];
    const float* osc_h      = (const float*)d_in[4];
    const float* init_w     = (const float*)d_in[5];
    const float* init_kappa = (const float*)d_in[6];
    const float* r1_jx_W = (const float*)d_in[7];
    const float* r1_jx_b = (const float*)d_in[8];
    const float* r1_jh_W = (const float*)d_in[9];
    const float* r1_jh_b = (const float*)d_in[10];
    const float* r1_kx_W = (const float*)d_in[11];
    const float* r1_kx_b = (const float*)d_in[12];
    const float* r1_kh_W = (const float*)d_in[13];
    const float* r1_kh_b = (const float*)d_in[14];
    const float* r2_jx_W = (const float*)d_in[15];
    const float* r2_jx_b = (const float*)d_in[16];
    const float* r2_jh_W = (const float*)d_in[17];
    const float* r2_jh_b = (const float*)d_in[18];
    const float* r2_kx_W = (const float*)d_in[19];
    const float* r2_kx_b = (const float*)d_in[20];
    const float* r2_kh_W = (const float*)d_in[21];
    const float* r2_kh_b = (const float*)d_in[22];
    const float* osc_jx_W = (const float*)d_in[23];
    const float* osc_jx_b = (const float*)d_in[24];
    const float* osc_jh_W = (const float*)d_in[25];
    const float* osc_jh_b = (const float*)d_in[26];
    const float* osc_kx_W = (const float*)d_in[27];
    const float* osc_kx_b = (const float*)d_in[28];
    const float* osc_kh_W = (const float*)d_in[29];
    const float* osc_kh_b = (const float*)d_in[30];
    const float* win_W = (const float*)d_in[31];
    const float* win_b = (const float*)d_in[32];
    const float* lin_W = (const float*)d_in[33];
    const float* lin_b = (const float*)d_in[34];

    float* out = (float*)d_out;
    unsigned short* ws = (unsigned short*)d_ws;

    // ws layout (ushort elements; all offsets 16B-aligned)
    unsigned short* X1   = ws;                               // 4096*672
    unsigned short* X2   = X1 + (size_t)BB_ * KP1;           // 4096*1184
    unsigned short* Xo   = X2 + (size_t)BB_ * KP2;           // 4*4096*1024
    unsigned short* Wj1  = Xo + (size_t)4 * BB_ * KPO;       // 512*672
    unsigned short* Wk1  = Wj1 + (size_t)512 * KP1;
    unsigned short* Wj2  = Wk1 + (size_t)512 * KP1;          // 512*1184
    unsigned short* Wk2  = Wj2 + (size_t)512 * KP2;
    unsigned short* WjO  = Wk2 + (size_t)512 * KP2;          // 4*512*1024
    unsigned short* WkO  = WjO + (size_t)4 * 512 * KPO;

    // ---- weight packing (independent of activations) ----
    pack_w<<<dim3(8, KP1 / 32, 1), 256, 0, stream>>>(r1_jx_W, 131, 0, r1_jh_W, 0, Wj1, KP1, 0);
    pack_w<<<dim3(8, KP1 / 32, 1), 256, 0, stream>>>(r1_kx_W, 131, 0, r1_kh_W, 0, Wk1, KP1, 0);
    pack_w<<<dim3(8, KP2 / 32, 1), 256, 0, stream>>>(r2_jx_W, 643, 0, r2_jh_W, 0, Wj2, KP2, 0);
    pack_w<<<dim3(8, KP2 / 32, 1), 256, 0, stream>>>(r2_kx_W, 643, 0, r2_kh_W, 0, Wk2, KP2, 0);
    pack_w<<<dim3(8, KPO / 32, 4), 256, 0, stream>>>(osc_jx_W, 512, (size_t)512 * 512, osc_jh_W, (size_t)512 * 512, WjO, KPO, (size_t)512 * KPO);
    pack_w<<<dim3(8, KPO / 32, 4), 256, 0, stream>>>(osc_kx_W, 512, (size_t)512 * 512, osc_kh_W, (size_t)512 * 512, WkO, KPO, (size_t)512 * KPO);

    // ---- rnn1 ----
    pack_x1<<<(BB_ * KP1 + 255) / 256, 256, 0, stream>>>(x, init_w, rnn_1_h, X1);
    gemm_gate<<<dim3(32, 4, 1), 256, 0, stream>>>(
        X1, 0, KP1, Wj1, Wk1, 0,
        r1_jx_b, r1_jh_b, r1_kx_b, r1_kh_b,
        rnn_1_h, 0, out + H1_OFF, 0);

    // ---- attention window -> kappa, phi, w ----
    win_kernel<<<BB_, 256, 0, stream>>>(out + H1_OFF, win_W, win_b,
                                        init_kappa, c_vec, out);

    // ---- rnn2 ----
    pack_x2<<<(BB_ * KP2 + 255) / 256, 256, 0, stream>>>(x, out + H1_OFF, out + W_OFF, rnn_2_h, X2);
    gemm_gate<<<dim3(32, 4, 1), 256, 0, stream>>>(
        X2, 0, KP2, Wj2, Wk2, 0,
        r2_jx_b, r2_jh_b, r2_kx_b, r2_kh_b,
        rnn_2_h, 0, out + H2_OFF, 0);

    // ---- oscillator gates ----
    pack_xosc<<<(4 * BB_ * KPO) / 256, 256, 0, stream>>>(out + H2_OFF, osc_h, Xo);
    gemm_gate<<<dim3(32, 4, 4), 256, 0, stream>>>(
        Xo, (size_t)BB_ * KPO, KPO, WjO, WkO, (size_t)512 * KPO,
        osc_jx_b, osc_jh_b, osc_kx_b, osc_kh_b,
        osc_h, (size_t)BB_ * SS_, out + OSC_OFF, (size_t)BB_ * SS_);

    // ---- oscillator recurrence + MDN head ----
    mdn_kernel<<<BB_ / 4, 256, 0, stream>>>(out + OSC_OFF, lin_W, lin_b, out);
}

// Round 4
// 1094.964 us; speedup vs baseline: 1.7813x; 1.0994x over previous
//
#include <hip/hip_runtime.h>
#include <math.h>

#define BB_ 4096
#define SS_ 512
#define KK_ 10
#define MM_ 20
#define UU_ 256
#define CC_ 128

// d_out flat offsets (floats), in reference return order
#define EOS_OFF   0
#define PI_OFF    20480
#define MU1_OFF   430080
#define MU2_OFF   839680
#define S1_OFF    1249280
#define S2_OFF    1658880
#define RHO_OFF   2068480
#define H1_OFF    2478080
#define H2_OFF    4575232
#define OSC_OFF   6672384
#define W_OFF     15060992
#define PHI_OFF   15585280
#define KAPPA_OFF 16633856

// Padded K sizes (multiples of 32)
#define KP1 672     // rnn1: 3 + 128 + 512 = 643 -> 672
#define KP2 1184    // rnn2: 3 + 512 + 128 + 512 = 1155 -> 1184
#define KPO 1024    // osc: 512 + 512

typedef __attribute__((ext_vector_type(8))) short s8b;   // 8 x bf16
typedef __attribute__((ext_vector_type(4))) float f4;    // 4 x f32

__device__ __forceinline__ float sigmoidf_(float x) {
    return 1.0f / (1.0f + __expf(-x));
}

__device__ __forceinline__ unsigned short f2b(float v) {
    union { float f; unsigned int u; } c; c.f = v;
    unsigned int r = (c.u + 0x7FFFu + ((c.u >> 16) & 1u)) >> 16;
    return (unsigned short)r;
}

// ---------------------------------------------------------------------------
// Pack X1 = [x(3) | init_w(128) | rnn_1_h(512) | 0-pad] -> bf16 [4096][672]
// ---------------------------------------------------------------------------
__global__ __launch_bounds__(256) void pack_x1(
    const float* __restrict__ x, const float* __restrict__ init_w,
    const float* __restrict__ h, unsigned short* __restrict__ X)
{
    int idx = blockIdx.x * 256 + threadIdx.x;
    if (idx >= BB_ * KP1) return;
    int b = idx / KP1, c = idx - b * KP1;
    float v = 0.0f;
    if (c < 3)        v = x[b * 3 + c];
    else if (c < 131) v = init_w[b * 128 + (c - 3)];
    else if (c < 643) v = h[b * 512 + (c - 131)];
    X[idx] = f2b(v);
}

// Pack X2 = [x(3) | h1(512) | w(128) | rnn_2_h(512) | 0-pad] -> bf16 [4096][1184]
__global__ __launch_bounds__(256) void pack_x2(
    const float* __restrict__ x, const float* __restrict__ h1,
    const float* __restrict__ w, const float* __restrict__ h2p,
    unsigned short* __restrict__ X)
{
    int idx = blockIdx.x * 256 + threadIdx.x;
    if (idx >= BB_ * KP2) return;
    int b = idx / KP2, c = idx - b * KP2;
    float v = 0.0f;
    if (c < 3)         v = x[b * 3 + c];
    else if (c < 515)  v = h1[b * 512 + (c - 3)];
    else if (c < 643)  v = w[b * 128 + (c - 515)];
    else if (c < 1155) v = h2p[b * 512 + (c - 643)];
    X[idx] = f2b(v);
}

// Pack Xosc[z] = [h2(512) | osc_h[z](512)] -> bf16 [4][4096][1024], short8 stores
__global__ __launch_bounds__(256) void pack_xosc(
    const float* __restrict__ h2, const float* __restrict__ osc_h,
    unsigned short* __restrict__ X)
{
    int t = blockIdx.x * 256 + threadIdx.x;    // 2,097,152 threads
    int c0 = (t << 3) & 1023;
    int b = (t >> 7) & 4095;
    int z = t >> 19;
    const float* src = (c0 < 512) ? h2 + (size_t)b * 512 + c0
                                  : osc_h + ((size_t)z * BB_ + b) * 512 + (c0 - 512);
    f4 v0 = *(const f4*)src;
    f4 v1 = *(const f4*)(src + 4);
    union { unsigned short u[8]; uint4 q; } o;
    o.u[0] = f2b(v0.x); o.u[1] = f2b(v0.y); o.u[2] = f2b(v0.z); o.u[3] = f2b(v0.w);
    o.u[4] = f2b(v1.x); o.u[5] = f2b(v1.y); o.u[6] = f2b(v1.z); o.u[7] = f2b(v1.w);
    *(uint4*)&X[(size_t)t * 8] = o.q;
}

// ---------------------------------------------------------------------------
// Pack + transpose weights: dst[z][nc][k] (bf16, [512][Kp])
// ---------------------------------------------------------------------------
__global__ __launch_bounds__(256) void pack_w(
    const float* __restrict__ src_x, int d1, size_t sxz,
    const float* __restrict__ src_h, size_t shz,
    unsigned short* __restrict__ dst, int Kp, size_t dz)
{
    __shared__ float t[32][65];
    const int tid = threadIdx.x;
    const int nc0 = blockIdx.x * 64;
    const int k0 = blockIdx.y * 32;
    const int z = blockIdx.z;
    const float* sx = src_x + (size_t)z * sxz;
    const float* sh = src_h + (size_t)z * shz;
    unsigned short* dd = dst + (size_t)z * dz;

    for (int i = tid; i < 64 * 32; i += 256) {
        int ncl = i & 63, kl = i >> 6;
        int k = k0 + kl;
        float v = 0.0f;
        if (k < d1)            v = sx[(size_t)k * 512 + nc0 + ncl];
        else if (k < d1 + 512) v = sh[(size_t)(k - d1) * 512 + nc0 + ncl];
        t[kl][ncl] = v;
    }
    __syncthreads();
    for (int i = tid; i < 64 * 32; i += 256) {
        int kl = i & 31, ncl = i >> 5;
        dd[(size_t)(nc0 + ncl) * Kp + k0 + kl] = f2b(t[kl][ncl]);
    }
}

// Pack lin_W [512][121] fp32 -> Wl [128][512] bf16 (transposed, col-padded)
__global__ __launch_bounds__(256) void pack_lin(
    const float* __restrict__ linW, unsigned short* __restrict__ Wl)
{
    __shared__ float t[32][65];
    const int tid = threadIdx.x;
    const int n0 = blockIdx.x * 64;
    const int k0 = blockIdx.y * 32;
    for (int i = tid; i < 64 * 32; i += 256) {
        int ncl = i & 63, kl = i >> 6;
        int n = n0 + ncl;
        t[kl][ncl] = (n < 121) ? linW[(size_t)(k0 + kl) * 121 + n] : 0.0f;
    }
    __syncthreads();
    for (int i = tid; i < 64 * 32; i += 256) {
        int kl = i & 31, ncl = i >> 5;
        Wl[(size_t)(n0 + ncl) * 512 + k0 + kl] = f2b(t[kl][ncl]);
    }
}

// ---------------------------------------------------------------------------
// MFMA gated-cell GEMM (unchanged from round 3 — verified)
// ---------------------------------------------------------------------------
__global__ __launch_bounds__(256) void gemm_gate(
    const unsigned short* __restrict__ A, size_t az, int Kp,
    const unsigned short* __restrict__ Wj, const unsigned short* __restrict__ Wk, size_t wz,
    const float* __restrict__ jxb, const float* __restrict__ jhb,
    const float* __restrict__ kxb, const float* __restrict__ khb,
    const float* __restrict__ h_prev, size_t hz,
    float* __restrict__ out, size_t oz)
{
    __shared__ unsigned short As[128 * 40];
    __shared__ unsigned short Bjs[128 * 40];
    __shared__ unsigned short Bks[128 * 40];

    const int tid = threadIdx.x;
    const int lane = tid & 63;
    const int w = tid >> 6;
    const int wr = w >> 1, wc = w & 1;
    const int b0 = blockIdx.x * 128;
    const int s0 = blockIdx.y * 128;
    const int z = blockIdx.z;

    const unsigned short* Az = A + (size_t)z * az;
    const unsigned short* Wjz = Wj + (size_t)z * wz;
    const unsigned short* Wkz = Wk + (size_t)z * wz;

    f4 accj[4][4], acck[4][4];
#pragma unroll
    for (int m = 0; m < 4; m++)
#pragma unroll
        for (int c = 0; c < 4; c++) {
            accj[m][c] = (f4)0.0f;
            acck[m][c] = (f4)0.0f;
        }

    const int lr = lane & 15;
    const int ks = (lane >> 4) * 8;
    const int nK = Kp >> 5;

    for (int kt = 0; kt < nK; kt++) {
        const int k0 = kt * 32;
#pragma unroll
        for (int i = tid; i < 512; i += 256) {
            int row = i >> 2, seg = i & 3;
            *(uint4*)&As[row * 40 + seg * 8] =
                *(const uint4*)(Az + (size_t)(b0 + row) * Kp + k0 + seg * 8);
            *(uint4*)&Bjs[row * 40 + seg * 8] =
                *(const uint4*)(Wjz + (size_t)(s0 + row) * Kp + k0 + seg * 8);
            *(uint4*)&Bks[row * 40 + seg * 8] =
                *(const uint4*)(Wkz + (size_t)(s0 + row) * Kp + k0 + seg * 8);
        }
        __syncthreads();

        s8b af[4], bjf[4], bkf[4];
#pragma unroll
        for (int m = 0; m < 4; m++)
            af[m] = *(const s8b*)&As[(wr * 64 + m * 16 + lr) * 40 + ks];
#pragma unroll
        for (int c = 0; c < 4; c++) {
            bjf[c] = *(const s8b*)&Bjs[(wc * 64 + c * 16 + lr) * 40 + ks];
            bkf[c] = *(const s8b*)&Bks[(wc * 64 + c * 16 + lr) * 40 + ks];
        }
#pragma unroll
        for (int m = 0; m < 4; m++)
#pragma unroll
            for (int c = 0; c < 4; c++) {
                accj[m][c] = __builtin_amdgcn_mfma_f32_16x16x32_bf16(af[m], bjf[c], accj[m][c], 0, 0, 0);
                acck[m][c] = __builtin_amdgcn_mfma_f32_16x16x32_bf16(af[m], bkf[c], acck[m][c], 0, 0, 0);
            }
        __syncthreads();
    }

    const float* hp = h_prev + (size_t)z * hz;
    float* op = out + (size_t)z * oz;
    const int zb = z * 512;
#pragma unroll
    for (int c = 0; c < 4; c++) {
        const int scol = s0 + wc * 64 + c * 16 + lr;
        const float bj = jxb[zb + scol] + jhb[zb + scol];
        const float bk = kxb[zb + scol] + khb[zb + scol];
#pragma unroll
        for (int m = 0; m < 4; m++) {
            const int r0 = b0 + wr * 64 + m * 16 + (lane >> 4) * 4;
#pragma unroll
            for (int reg = 0; reg < 4; reg++) {
                const int r = r0 + reg;
                const float h = hp[(size_t)r * 512 + scol];
                const float jv = sigmoidf_(accj[m][c][reg] + bj);
                const float kv = sigmoidf_(acck[m][c][reg] + bk);
                op[(size_t)r * 512 + scol] = jv * (1.0f - h) + (1.0f - kv) * h;
            }
        }
    }
}

// ---------------------------------------------------------------------------
// Gaussian window attention: one block per batch row. PV loop = float4 loads.
// ---------------------------------------------------------------------------
__global__ __launch_bounds__(256) void win_kernel(
    const float* __restrict__ h1,
    const float* __restrict__ winW, const float* __restrict__ winb,
    const float* __restrict__ init_kappa,
    const float* __restrict__ c_vec,
    float* __restrict__ out)
{
    __shared__ float hl[512];
    __shared__ float part[8][30];
    __shared__ float kg[30];
    __shared__ float alpha_s[10], beta_s[10], kap_s[10];
    __shared__ float phil[256];
    __shared__ f4 wacc[8][32];

    const int tid = threadIdx.x;
    const int b = blockIdx.x;

    hl[tid] = h1[b * 512 + tid];
    hl[256 + tid] = h1[b * 512 + 256 + tid];
    __syncthreads();

    if (tid < 240) {
        int c = tid % 30, p = tid / 30;
        float a = 0.0f;
        int s0 = p * 64;
#pragma unroll 4
        for (int i = 0; i < 64; i++) a = fmaf(hl[s0 + i], winW[(s0 + i) * 30 + c], a);
        part[p][c] = a;
    }
    __syncthreads();
    if (tid < 30) {
        float a = winb[tid];
#pragma unroll
        for (int p = 0; p < 8; p++) a += part[p][tid];
        kg[tid] = a;
    }
    __syncthreads();
    if (tid < 10) {
        alpha_s[tid] = __expf(kg[tid]);
        beta_s[tid] = __expf(kg[10 + tid]);
        float kp = init_kappa[b * 10 + tid] + __expf(kg[20 + tid]);
        kap_s[tid] = kp;
        out[KAPPA_OFF + b * 10 + tid] = kp;
    }
    __syncthreads();
    {
        float u = (float)tid;
        float p = 0.0f;
#pragma unroll
        for (int k = 0; k < 10; k++) {
            float d = kap_s[k] - u;
            p += alpha_s[k] * __expf(-beta_s[k] * d * d);
        }
        phil[tid] = p;
        out[PHI_OFF + b * 256 + tid] = p;
    }
    __syncthreads();
    {
        // w[c] = sum_u phi[u] * c_vec[b,u,c] : lane owns 4 cols, 8 u-groups
        const int c4 = tid & 31, ug = tid >> 5;
        const f4* cv4 = (const f4*)(c_vec + (size_t)b * UU_ * CC_);
        f4 a4 = (f4)0.0f;
#pragma unroll 4
        for (int i = 0; i < 32; i++) {
            int u = ug * 32 + i;
            f4 v = cv4[(size_t)u * 32 + c4];
            float p = phil[u];
            a4 += v * p;
        }
        wacc[ug][c4] = a4;
    }
    __syncthreads();
    if (tid < 32) {
        f4 s = wacc[0][tid];
#pragma unroll
        for (int g = 1; g < 8; g++) s += wacc[g][tid];
        *(f4*)(out + W_OFF + (size_t)b * CC_ + tid * 4) = s;
    }
}

// ---------------------------------------------------------------------------
// MDN head via MFMA: 16 batch rows (80 MDN rows) per block, grid 256.
// A = 5-step oscillator recurrence (computed tile-wise into LDS, bf16);
// B = Wl [128][512] bf16 (pre-transposed lin_W, cols padded 121->128).
// Epilogue: acc -> LDS f32, then scalar eos/softmax/exp/tanh per row.
// ---------------------------------------------------------------------------
__global__ __launch_bounds__(256) void mdn_kernel(
    const float* __restrict__ osc_new,
    const unsigned short* __restrict__ Wl, const float* __restrict__ linb,
    float* __restrict__ out)
{
    __shared__ float epi[80][133];                       // 42.6 KB (reused for staging)
    __shared__ float lbs[121];
    unsigned short* As = (unsigned short*)&epi[0][0];    // [80][40] bf16 = 6.4 KB
    unsigned short* Bs = As + 80 * 40;                   // [128][40] bf16 = 10.2 KB

    const int tid = threadIdx.x;
    const int lane = tid & 63;
    const int w = tid >> 6;          // wave id: cols w*32..w*32+31
    const int lr = lane & 15;
    const int ks = (lane >> 4) * 8;
    const int b0 = blockIdx.x * 16;  // 16 batch rows -> 80 MDN rows

    if (tid < 121) lbs[tid] = linb[tid];

    f4 acc[5][2];
#pragma unroll
    for (int m = 0; m < 5; m++)
#pragma unroll
        for (int n = 0; n < 2; n++) acc[m][n] = (f4)0.0f;

    for (int kt = 0; kt < 16; kt++) {
        const int k0 = kt * 32;
        // stage A: recurrence for (16 b) x (32 s), 5 time rows each
#pragma unroll
        for (int t = 0; t < 2; t++) {
            int task = tid + t * 256;
            int bl = task >> 5, sl = task & 31;
            int b = b0 + bl, s = k0 + sl;
            float ph = osc_new[(size_t)0 * BB_ * SS_ + (size_t)b * SS_ + s];
            float om = osc_new[(size_t)1 * BB_ * SS_ + (size_t)b * SS_ + s];
            float r  = osc_new[(size_t)2 * BB_ * SS_ + (size_t)b * SS_ + s];
            float mu = osc_new[(size_t)3 * BB_ * SS_ + (size_t)b * SS_ + s];
            As[(bl * 5 + 0) * 40 + sl] = f2b(r * __cosf(ph));
#pragma unroll
            for (int tt = 1; tt < 5; tt++) {
                r = fmaf(mu - r * r, r, r);
                ph += om;
                As[(bl * 5 + tt) * 40 + sl] = f2b(r * __cosf(ph));
            }
        }
        // stage B
#pragma unroll
        for (int i = tid; i < 512; i += 256) {
            int row = i >> 2, seg = i & 3;
            *(uint4*)&Bs[row * 40 + seg * 8] =
                *(const uint4*)(Wl + (size_t)row * 512 + k0 + seg * 8);
        }
        __syncthreads();

        s8b a[5], bf[2];
#pragma unroll
        for (int m = 0; m < 5; m++)
            a[m] = *(const s8b*)&As[(m * 16 + lr) * 40 + ks];
#pragma unroll
        for (int n = 0; n < 2; n++)
            bf[n] = *(const s8b*)&Bs[(w * 32 + n * 16 + lr) * 40 + ks];
#pragma unroll
        for (int m = 0; m < 5; m++)
#pragma unroll
            for (int n = 0; n < 2; n++)
                acc[m][n] = __builtin_amdgcn_mfma_f32_16x16x32_bf16(a[m], bf[n], acc[m][n], 0, 0, 0);
        __syncthreads();
    }

    // dump acc to epi (overwrites As/Bs — all LDS reads done)
#pragma unroll
    for (int m = 0; m < 5; m++)
#pragma unroll
        for (int n = 0; n < 2; n++) {
            const int col = w * 32 + n * 16 + lr;
#pragma unroll
            for (int reg = 0; reg < 4; reg++) {
                const int row = m * 16 + (lane >> 4) * 4 + reg;
                epi[row][col] = acc[m][n][reg];
            }
        }
    __syncthreads();

    if (tid < 80) {
        const int rg = b0 * 5 + tid;
        const float* o = epi[tid];
        out[EOS_OFF + rg] = 1.0f / (1.0f + __expf(o[0] + lbs[0]));
        float mx = -1e30f;
        float pv[20];
#pragma unroll
        for (int m = 0; m < 20; m++) {
            pv[m] = o[1 + m] + lbs[1 + m];
            mx = fmaxf(mx, pv[m]);
        }
        float sum = 0.0f;
#pragma unroll
        for (int m = 0; m < 20; m++) { pv[m] = __expf(pv[m] - mx); sum += pv[m]; }
        float inv = 1.0f / sum;
#pragma unroll
        for (int m = 0; m < 20; m++) {
            out[PI_OFF  + rg * 20 + m] = pv[m] * inv;
            out[MU1_OFF + rg * 20 + m] = o[21 + m] + lbs[21 + m];
            out[MU2_OFF + rg * 20 + m] = o[41 + m] + lbs[41 + m];
            out[S1_OFF  + rg * 20 + m] = __expf(o[61 + m] + lbs[61 + m]);
            out[S2_OFF  + rg * 20 + m] = __expf(o[81 + m] + lbs[81 + m]);
            out[RHO_OFF + rg * 20 + m] = tanhf(o[101 + m] + lbs[101 + m]);
        }
    }
}

// ---------------------------------------------------------------------------
extern "C" void kernel_launch(void* const* d_in, const int* in_sizes, int n_in,
                              void* d_out, int out_size, void* d_ws, size_t ws_size,
                              hipStream_t stream)
{
    const float* x          = (const float*)d_in[0];
    const float* c_vec      = (const float*)d_in[1];
    const float* rnn_1_h    = (const float*)d_in[2];
    const float* rnn_2_h    = (const float*)d_in[3];
    const float* osc_h      = (const float*)d_in[4];
    const float* init_w     = (const float*)d_in[5];
    const float* init_kappa = (const float*)d_in[6];
    const float* r1_jx_W = (const float*)d_in[7];
    const float* r1_jx_b = (const float*)d_in[8];
    const float* r1_jh_W = (const float*)d_in[9];
    const float* r1_jh_b = (const float*)d_in[10];
    const float* r1_kx_W = (const float*)d_in[11];
    const float* r1_kx_b = (const float*)d_in[12];
    const float* r1_kh_W = (const float*)d_in[13];
    const float* r1_kh_b = (const float*)d_in[14];
    const float* r2_jx_W = (const float*)d_in[15];
    const float* r2_jx_b = (const float*)d_in[16];
    const float* r2_jh_W = (const float*)d_in[17];
    const float* r2_jh_b = (const float*)d_in[18];
    const float* r2_kx_W = (const float*)d_in[19];
    const float* r2_kx_b = (const float*)d_in[20];
    const float* r2_kh_W = (const float*)d_in[21];
    const float* r2_kh_b = (const float*)d_in[22];
    const float* osc_jx_W = (const float*)d_in[23];
    const float* osc_jx_b = (const float*)d_in[24];
    const float* osc_jh_W = (const float*)d_in[25];
    const float* osc_jh_b = (const float*)d_in[26];
    const float* osc_kx_W = (const float*)d_in[27];
    const float* osc_kx_b = (const float*)d_in[28];
    const float* osc_kh_W = (const float*)d_in[29];
    const float* osc_kh_b = (const float*)d_in[30];
    const float* win_W = (const float*)d_in[31];
    const float* win_b = (const float*)d_in[32];
    const float* lin_W = (const float*)d_in[33];
    const float* lin_b = (const float*)d_in[34];

    float* out = (float*)d_out;
    unsigned short* ws = (unsigned short*)d_ws;

    // ws layout (ushort elements; all offsets 16B-aligned)
    unsigned short* X1   = ws;                               // 4096*672
    unsigned short* X2   = X1 + (size_t)BB_ * KP1;           // 4096*1184
    unsigned short* Xo   = X2 + (size_t)BB_ * KP2;           // 4*4096*1024
    unsigned short* Wj1  = Xo + (size_t)4 * BB_ * KPO;       // 512*672
    unsigned short* Wk1  = Wj1 + (size_t)512 * KP1;
    unsigned short* Wj2  = Wk1 + (size_t)512 * KP1;          // 512*1184
    unsigned short* Wk2  = Wj2 + (size_t)512 * KP2;
    unsigned short* WjO  = Wk2 + (size_t)512 * KP2;          // 4*512*1024
    unsigned short* WkO  = WjO + (size_t)4 * 512 * KPO;
    unsigned short* Wl   = WkO + (size_t)4 * 512 * KPO;      // 128*512

    // ---- weight packing (independent of activations) ----
    pack_w<<<dim3(8, KP1 / 32, 1), 256, 0, stream>>>(r1_jx_W, 131, 0, r1_jh_W, 0, Wj1, KP1, 0);
    pack_w<<<dim3(8, KP1 / 32, 1), 256, 0, stream>>>(r1_kx_W, 131, 0, r1_kh_W, 0, Wk1, KP1, 0);
    pack_w<<<dim3(8, KP2 / 32, 1), 256, 0, stream>>>(r2_jx_W, 643, 0, r2_jh_W, 0, Wj2, KP2, 0);
    pack_w<<<dim3(8, KP2 / 32, 1), 256, 0, stream>>>(r2_kx_W, 643, 0, r2_kh_W, 0, Wk2, KP2, 0);
    pack_w<<<dim3(8, KPO / 32, 4), 256, 0, stream>>>(osc_jx_W, 512, (size_t)512 * 512, osc_jh_W, (size_t)512 * 512, WjO, KPO, (size_t)512 * KPO);
    pack_w<<<dim3(8, KPO / 32, 4), 256, 0, stream>>>(osc_kx_W, 512, (size_t)512 * 512, osc_kh_W, (size_t)512 * 512, WkO, KPO, (size_t)512 * KPO);
    pack_lin<<<dim3(2, 16), 256, 0, stream>>>(lin_W, Wl);

    // ---- rnn1 ----
    pack_x1<<<(BB_ * KP1 + 255) / 256, 256, 0, stream>>>(x, init_w, rnn_1_h, X1);
    gemm_gate<<<dim3(32, 4, 1), 256, 0, stream>>>(
        X1, 0, KP1, Wj1, Wk1, 0,
        r1_jx_b, r1_jh_b, r1_kx_b, r1_kh_b,
        rnn_1_h, 0, out + H1_OFF, 0);

    // ---- attention window -> kappa, phi, w ----
    win_kernel<<<BB_, 256, 0, stream>>>(out + H1_OFF, win_W, win_b,
                                        init_kappa, c_vec, out);

    // ---- rnn2 ----
    pack_x2<<<(BB_ * KP2 + 255) / 256, 256, 0, stream>>>(x, out + H1_OFF, out + W_OFF, rnn_2_h, X2);
    gemm_gate<<<dim3(32, 4, 1), 256, 0, stream>>>(
        X2, 0, KP2, Wj2, Wk2, 0,
        r2_jx_b, r2_jh_b, r2_kx_b, r2_kh_b,
        rnn_2_h, 0, out + H2_OFF, 0);

    // ---- oscillator gates ----
    pack_xosc<<<(4 * BB_ * KPO) / (8 * 256), 256, 0, stream>>>(out + H2_OFF, osc_h, Xo);
    gemm_gate<<<dim3(32, 4, 4), 256, 0, stream>>>(
        Xo, (size_t)BB_ * KPO, KPO, WjO, WkO, (size_t)512 * KPO,
        osc_jx_b, osc_jh_b, osc_kx_b, osc_kh_b,
        osc_h, (size_t)BB_ * SS_, out + OSC_OFF, (size_t)BB_ * SS_);

    // ---- oscillator recurrence + MDN head (MFMA) ----
    mdn_kernel<<<BB_ / 16, 256, 0, stream>>>(out + OSC_OFF, Wl, lin_b, out);
}